// Round 1
// baseline (841.321 us; speedup 1.0000x reference)
//
#include <hip/hip_runtime.h>
#include <hip/hip_bf16.h>

#define DIMC 1024
#define DH   64
#define NH   16
#define WIN  128
#define TT   8192
#define BB   4
#define NTOK 32768
#define NQKV 3072

typedef __hip_bfloat16 bf16;
typedef __attribute__((ext_vector_type(8))) __bf16 b16x8;
typedef __attribute__((ext_vector_type(4))) float  f32x4;

__device__ __forceinline__ void gload_lds16(const void* g, void* l) {
  __builtin_amdgcn_global_load_lds((__attribute__((address_space(1))) void*)g,
                                   (__attribute__((address_space(3))) void*)l,
                                   16, 0, 0);
}

// ---------------- LayerNorm stats (two-stage, coalesced along T) ------------
__global__ void k_stats_partial(const float* __restrict__ x,
                                float* __restrict__ psum, float* __restrict__ psq) {
  int g = blockIdx.x * 256 + threadIdx.x;   // global token id
  int s = blockIdx.y;                        // channel split 0..7
  int b = g >> 13;
  int t = g & (TT - 1);
  const float* xp = x + ((size_t)b * DIMC + s * 128) * TT + t;
  float sum = 0.f, sq = 0.f;
  for (int c = 0; c < 128; c++) {
    float v = xp[(size_t)c * TT];
    sum += v; sq += v * v;
  }
  psum[s * NTOK + g] = sum;
  psq [s * NTOK + g] = sq;
}

__global__ void k_stats_final(const float* __restrict__ psum, const float* __restrict__ psq,
                              float* __restrict__ mean, float* __restrict__ rstd) {
  int g = blockIdx.x * 256 + threadIdx.x;
  float s = 0.f, q = 0.f;
  for (int i = 0; i < 8; i++) { s += psum[i * NTOK + g]; q += psq[i * NTOK + g]; }
  float mu = s * (1.0f / 1024.0f);
  float var = q * (1.0f / 1024.0f) - mu * mu;
  mean[g] = mu;
  rstd[g] = rsqrtf(var + 1e-5f);
}

// ------- transpose (B,C,T)->(B*T,C) + LayerNorm + bf16 cast -----------------
__global__ void k_norm_t(const float* __restrict__ x, const float* __restrict__ mean,
                         const float* __restrict__ rstd, const float* __restrict__ lnw,
                         const float* __restrict__ lnb, bf16* __restrict__ h) {
  __shared__ float tile[32][33];
  int b = blockIdx.z, c0 = blockIdx.y * 32, t0 = blockIdx.x * 32;
  int col = threadIdx.x & 31, rr = threadIdx.x >> 5;
  for (int i = 0; i < 4; i++) {
    int c = rr + i * 8;
    tile[c][col] = x[((size_t)b * DIMC + c0 + c) * TT + t0 + col];
  }
  __syncthreads();
  for (int i = 0; i < 4; i++) {
    int t = rr + i * 8;
    int g = b * TT + t0 + t;
    float mu = mean[g], rs = rstd[g];
    float v = (tile[col][t] - mu) * rs * lnw[c0 + col] + lnb[c0 + col];
    h[((size_t)(b * TT + t0 + t)) * DIMC + c0 + col] = __float2bfloat16(v);
  }
}

// ---------------- weight fp32 -> bf16 cast ----------------------------------
__global__ void k_cast(const float* __restrict__ wqkv, const float* __restrict__ wout,
                       bf16* __restrict__ wqkvb, bf16* __restrict__ woutb) {
  size_t i = (size_t)blockIdx.x * 256 + threadIdx.x;
  if (i < (size_t)NQKV * DIMC) wqkvb[i] = __float2bfloat16(wqkv[i]);
  if (i < (size_t)DIMC * DIMC) woutb[i] = __float2bfloat16(wout[i]);
}

// ---------------- bf16 GEMM, C[M,N] = A[M,K] * B[N,K]^T ---------------------
// 128x128 tile, BK=32, 4 waves each owning 64x64 (4x4 16x16x32 MFMA tiles)
__global__ __launch_bounds__(256) void k_gemm_bt(const bf16* __restrict__ A,
                                                 const bf16* __restrict__ Bm,
                                                 bf16* __restrict__ C,
                                                 int M, int N, int K) {
  __shared__ __align__(16) bf16 As[128 * 32];
  __shared__ __align__(16) bf16 Bs[128 * 32];
  int tid = threadIdx.x;
  int wave = tid >> 6, lane = tid & 63;
  int m0 = blockIdx.y * 128, n0 = blockIdx.x * 128;
  int wm = (wave >> 1) * 64, wn = (wave & 1) * 64;
  int lr = lane & 15, quad = lane >> 4;
  int srow = lane >> 2;           // staging: 4 lanes per row
  int scol = (lane & 3) * 8;      // 8 bf16 = 16B per lane

  f32x4 acc[4][4];
#pragma unroll
  for (int i = 0; i < 4; i++)
#pragma unroll
    for (int j = 0; j < 4; j++) acc[i][j] = (f32x4){0.f, 0.f, 0.f, 0.f};

  for (int k0 = 0; k0 < K; k0 += 32) {
#pragma unroll
    for (int r = 0; r < 2; r++) {
      int chunk = r * 4 + wave;          // wave-uniform
      int row = chunk * 16 + srow;
      gload_lds16(A  + (size_t)(m0 + row) * K + k0 + scol, As + row * 32 + scol);
      gload_lds16(Bm + (size_t)(n0 + row) * K + k0 + scol, Bs + row * 32 + scol);
    }
    __syncthreads();
    b16x8 af[4], bfr[4];
#pragma unroll
    for (int i = 0; i < 4; i++) af[i]  = *(const b16x8*)(As + (wm + i * 16 + lr) * 32 + quad * 8);
#pragma unroll
    for (int j = 0; j < 4; j++) bfr[j] = *(const b16x8*)(Bs + (wn + j * 16 + lr) * 32 + quad * 8);
#pragma unroll
    for (int i = 0; i < 4; i++)
#pragma unroll
      for (int j = 0; j < 4; j++)
        acc[i][j] = __builtin_amdgcn_mfma_f32_16x16x32_bf16(af[i], bfr[j], acc[i][j], 0, 0, 0);
    __syncthreads();
  }

#pragma unroll
  for (int i = 0; i < 4; i++)
#pragma unroll
    for (int j = 0; j < 4; j++) {
      int row = m0 + wm + i * 16 + quad * 4;
      int col = n0 + wn + j * 16 + lr;
      bf16* cp = C + (size_t)row * N + col;
#pragma unroll
      for (int r = 0; r < 4; r++) cp[(size_t)r * N] = __float2bfloat16(acc[i][j][r]);
    }
}

// ---------------- attention: one block per (b, head, window) ----------------
__global__ __launch_bounds__(256) void k_attn(const bf16* __restrict__ qkv,
                                              bf16* __restrict__ att) {
  // LDS plan (bytes): qs[128][72] @0 (18432), ks[128][72] @18432 (18432),
  // vt[64][136] @36864 (17408), ps[128][136] overlaps qs+ks @0 (34816)
  __shared__ __align__(16) char smem[54272];
  bf16* qs = (bf16*)smem;
  bf16* ks = (bf16*)(smem + 18432);
  bf16* vt = (bf16*)(smem + 36864);
  bf16* ps = (bf16*)smem;

  const int tid = threadIdx.x;
  const int wdw = blockIdx.x, hh = blockIdx.y, b = blockIdx.z;
  const size_t base = ((size_t)(b * TT + wdw * WIN)) * NQKV + hh * DH;

  // load q,k with fused RoPE (pos = row within window)
  for (int idx = tid; idx < 128 * 32; idx += 256) {
    int row = idx >> 5, j = idx & 31;
    float invf = exp2f(-0.41524101186f * (float)j);  // 10000^(-2j/64)
    float fr = (float)row * invf;
    float sv, cv;
    __sincosf(fr, &sv, &cv);
    const bf16* qp = qkv + base + (size_t)row * NQKV;
    float q0 = __bfloat162float(qp[j]);
    float q1 = __bfloat162float(qp[j + 32]);
    qs[row * 72 + j]      = __float2bfloat16(q0 * cv - q1 * sv);
    qs[row * 72 + j + 32] = __float2bfloat16(q1 * cv + q0 * sv);
    float ka = __bfloat162float(qp[1024 + j]);
    float kb = __bfloat162float(qp[1024 + j + 32]);
    ks[row * 72 + j]      = __float2bfloat16(ka * cv - kb * sv);
    ks[row * 72 + j + 32] = __float2bfloat16(kb * cv + ka * sv);
  }
  // load v transposed: vt[d][token]
  for (int idx = tid; idx < 128 * 64; idx += 256) {
    int row = idx >> 6, d = idx & 63;
    vt[d * 136 + row] = qkv[base + (size_t)row * NQKV + 2048 + d];
  }
  __syncthreads();

  const int wid = tid >> 6, lane = tid & 63;
  const int lr = lane & 15, quad = lane >> 4;

  // S = q k^T : each wave owns a 32x128 strip
  f32x4 sa[2][8];
#pragma unroll
  for (int i = 0; i < 2; i++)
#pragma unroll
    for (int nt = 0; nt < 8; nt++) sa[i][nt] = (f32x4){0.f, 0.f, 0.f, 0.f};

  b16x8 aq[2][2];
#pragma unroll
  for (int i = 0; i < 2; i++)
#pragma unroll
    for (int s = 0; s < 2; s++)
      aq[i][s] = *(const b16x8*)(qs + (wid * 32 + i * 16 + lr) * 72 + s * 32 + quad * 8);
#pragma unroll
  for (int nt = 0; nt < 8; nt++) {
    b16x8 b0 = *(const b16x8*)(ks + (nt * 16 + lr) * 72 + quad * 8);
    b16x8 b1 = *(const b16x8*)(ks + (nt * 16 + lr) * 72 + 32 + quad * 8);
#pragma unroll
    for (int i = 0; i < 2; i++) {
      sa[i][nt] = __builtin_amdgcn_mfma_f32_16x16x32_bf16(aq[i][0], b0, sa[i][nt], 0, 0, 0);
      sa[i][nt] = __builtin_amdgcn_mfma_f32_16x16x32_bf16(aq[i][1], b1, sa[i][nt], 0, 0, 0);
    }
  }
  __syncthreads();  // qs/ks reads done; ps overwrites them

  // softmax per row (rows live in C/D layout: row = quad*4+r, col = lane&15 + 16*nt)
#pragma unroll
  for (int i = 0; i < 2; i++) {
#pragma unroll
    for (int r = 0; r < 4; r++) {
      float vals[8];
      float mx = -1e30f;
#pragma unroll
      for (int nt = 0; nt < 8; nt++) { vals[nt] = sa[i][nt][r] * 0.125f; mx = fmaxf(mx, vals[nt]); }
      for (int m = 1; m < 16; m <<= 1) mx = fmaxf(mx, __shfl_xor(mx, m, 16));
      float sum = 0.f;
#pragma unroll
      for (int nt = 0; nt < 8; nt++) { vals[nt] = __expf(vals[nt] - mx); sum += vals[nt]; }
      for (int m = 1; m < 16; m <<= 1) sum += __shfl_xor(sum, m, 16);
      float inv = 1.0f / sum;
      int row = wid * 32 + i * 16 + quad * 4 + r;
#pragma unroll
      for (int nt = 0; nt < 8; nt++)
        ps[row * 136 + nt * 16 + lr] = __float2bfloat16(vals[nt] * inv);
    }
  }
  __syncthreads();

  // O = P V : wave owns 32 rows x 64 dims, K=128
  f32x4 oa[2][4];
#pragma unroll
  for (int i = 0; i < 2; i++)
#pragma unroll
    for (int nt = 0; nt < 4; nt++) oa[i][nt] = (f32x4){0.f, 0.f, 0.f, 0.f};
#pragma unroll
  for (int s = 0; s < 4; s++) {
    b16x8 ap[2];
#pragma unroll
    for (int i = 0; i < 2; i++)
      ap[i] = *(const b16x8*)(ps + (wid * 32 + i * 16 + lr) * 136 + s * 32 + quad * 8);
#pragma unroll
    for (int nt = 0; nt < 4; nt++) {
      b16x8 bv = *(const b16x8*)(vt + (nt * 16 + lr) * 136 + s * 32 + quad * 8);
#pragma unroll
      for (int i = 0; i < 2; i++)
        oa[i][nt] = __builtin_amdgcn_mfma_f32_16x16x32_bf16(ap[i], bv, oa[i][nt], 0, 0, 0);
    }
  }
#pragma unroll
  for (int i = 0; i < 2; i++)
#pragma unroll
    for (int nt = 0; nt < 4; nt++) {
      int row = wid * 32 + i * 16 + quad * 4;
#pragma unroll
      for (int r = 0; r < 4; r++)
        att[((size_t)(b * TT + wdw * WIN + row + r)) * DIMC + hh * DH + nt * 16 + lr] =
            __float2bfloat16(oa[i][nt][r]);
    }
}

// ---------- transpose back (B*T,C)->(B,C,T), add residual, fp32 out ---------
__global__ void k_out_res(const bf16* __restrict__ g, const float* __restrict__ x,
                          float* __restrict__ out) {
  __shared__ float tile[32][33];
  int b = blockIdx.z, c0 = blockIdx.y * 32, t0 = blockIdx.x * 32;
  int col = threadIdx.x & 31, rr = threadIdx.x >> 5;
  for (int i = 0; i < 4; i++) {
    int t = rr + i * 8;
    tile[t][col] = __bfloat162float(g[((size_t)(b * TT + t0 + t)) * DIMC + c0 + col]);
  }
  __syncthreads();
  for (int i = 0; i < 4; i++) {
    int c = rr + i * 8;
    size_t o = ((size_t)b * DIMC + c0 + c) * TT + t0 + col;
    out[o] = x[o] + tile[col][c];
  }
}

extern "C" void kernel_launch(void* const* d_in, const int* in_sizes, int n_in,
                              void* d_out, int out_size, void* d_ws, size_t ws_size,
                              hipStream_t stream) {
  const float* x    = (const float*)d_in[0];
  const float* lnw  = (const float*)d_in[1];
  const float* lnb  = (const float*)d_in[2];
  const float* wqkv = (const float*)d_in[3];
  const float* wout = (const float*)d_in[4];
  float* out = (float*)d_out;

  char* ws = (char*)d_ws;
  float* psum  = (float*)(ws);                                  // 1 MiB
  float* psq   = (float*)(ws + (size_t)1  * 1024 * 1024);      // 1 MiB
  float* meanp = (float*)(ws + (size_t)2  * 1024 * 1024);      // 128 KiB
  float* rstdp = (float*)(ws + (size_t)2  * 1024 * 1024 + 131072);
  bf16*  wqkvb = (bf16*) (ws + (size_t)4  * 1024 * 1024);      // 6 MiB
  bf16*  woutb = (bf16*) (ws + (size_t)10 * 1024 * 1024);      // 2 MiB
  bf16*  h     = (bf16*) (ws + (size_t)12 * 1024 * 1024);      // 64 MiB
  bf16*  qkv   = (bf16*) (ws + (size_t)76 * 1024 * 1024);      // 192 MiB
  bf16*  att   = h;    // h consumed by QKV GEMM before attention writes
  bf16*  g2    = qkv;  // qkv consumed by attention before out-proj writes

  k_stats_partial<<<dim3(NTOK / 256, 8), 256, 0, stream>>>(x, psum, psq);
  k_stats_final<<<dim3(NTOK / 256), 256, 0, stream>>>(psum, psq, meanp, rstdp);
  k_norm_t<<<dim3(TT / 32, DIMC / 32, BB), 256, 0, stream>>>(x, meanp, rstdp, lnw, lnb, h);
  k_cast<<<dim3((NQKV * DIMC) / 256), 256, 0, stream>>>(wqkv, wout, wqkvb, woutb);
  k_gemm_bt<<<dim3(NQKV / 128, NTOK / 128), 256, 0, stream>>>(h, wqkvb, qkv, NTOK, NQKV, DIMC);
  k_attn<<<dim3(TT / WIN, NH, BB), 256, 0, stream>>>(qkv, att);
  k_gemm_bt<<<dim3(DIMC / 128, NTOK / 128), 256, 0, stream>>>(att, woutb, g2, NTOK, DIMC, DIMC);
  k_out_res<<<dim3(TT / 32, DIMC / 32, BB), 256, 0, stream>>>(g2, x, out);
}

// Round 2
// 752.827 us; speedup vs baseline: 1.1175x; 1.1175x over previous
//
#include <hip/hip_runtime.h>
#include <hip/hip_bf16.h>

#define DIMC 1024
#define DH   64
#define NH   16
#define WIN  128
#define TT   8192
#define BB   4
#define NTOK 32768
#define NQKV 3072

typedef __hip_bfloat16 bf16;
typedef __attribute__((ext_vector_type(8))) __bf16 b16x8;
typedef __attribute__((ext_vector_type(4))) float  f32x4;

union BV { b16x8 v; bf16 h[8]; };

__device__ __forceinline__ void gload_lds16(const void* g, void* l) {
  __builtin_amdgcn_global_load_lds((__attribute__((address_space(1))) void*)g,
                                   (__attribute__((address_space(3))) void*)l,
                                   16, 0, 0);
}

// ---------------- LayerNorm stats (two-stage, float4 along T) ---------------
__global__ void k_stats_partial(const float* __restrict__ x,
                                float* __restrict__ psum, float* __restrict__ psq) {
  int g4 = blockIdx.x * 256 + threadIdx.x;   // token-quad id, 0..8191
  int s = blockIdx.y;                         // channel split 0..7
  int t4 = g4 * 4;
  int b = t4 >> 13;
  int t = t4 & (TT - 1);
  const float* xp = x + ((size_t)b * DIMC + s * 128) * TT + t;
  float4 sum = {0.f, 0.f, 0.f, 0.f}, sq = {0.f, 0.f, 0.f, 0.f};
  for (int c = 0; c < 128; c++) {
    float4 v = *(const float4*)(xp + (size_t)c * TT);
    sum.x += v.x; sum.y += v.y; sum.z += v.z; sum.w += v.w;
    sq.x += v.x * v.x; sq.y += v.y * v.y; sq.z += v.z * v.z; sq.w += v.w * v.w;
  }
  *(float4*)(psum + s * NTOK + t4) = sum;
  *(float4*)(psq  + s * NTOK + t4) = sq;
}

__global__ void k_stats_final(const float* __restrict__ psum, const float* __restrict__ psq,
                              float* __restrict__ mean, float* __restrict__ rstd) {
  int g4 = (blockIdx.x * 256 + threadIdx.x) * 4;
  float4 s = {0.f, 0.f, 0.f, 0.f}, q = {0.f, 0.f, 0.f, 0.f};
  for (int i = 0; i < 8; i++) {
    float4 a = *(const float4*)(psum + i * NTOK + g4);
    float4 bq = *(const float4*)(psq + i * NTOK + g4);
    s.x += a.x; s.y += a.y; s.z += a.z; s.w += a.w;
    q.x += bq.x; q.y += bq.y; q.z += bq.z; q.w += bq.w;
  }
  float4 mu = {s.x * (1.f/1024.f), s.y * (1.f/1024.f), s.z * (1.f/1024.f), s.w * (1.f/1024.f)};
  float4 rs;
  rs.x = rsqrtf(q.x * (1.f/1024.f) - mu.x * mu.x + 1e-5f);
  rs.y = rsqrtf(q.y * (1.f/1024.f) - mu.y * mu.y + 1e-5f);
  rs.z = rsqrtf(q.z * (1.f/1024.f) - mu.z * mu.z + 1e-5f);
  rs.w = rsqrtf(q.w * (1.f/1024.f) - mu.w * mu.w + 1e-5f);
  *(float4*)(mean + g4) = mu;
  *(float4*)(rstd + g4) = rs;
}

// ------- transpose (B,C,T)->(B*T,C) + LayerNorm + bf16 cast, 64x64 tile -----
__global__ __launch_bounds__(256) void k_norm_t(const float* __restrict__ x,
                         const float* __restrict__ mean, const float* __restrict__ rstd,
                         const float* __restrict__ lnw, const float* __restrict__ lnb,
                         bf16* __restrict__ h) {
  __shared__ float tile[64][65];
  int b = blockIdx.z, c0 = blockIdx.y * 64, t0 = blockIdx.x * 64;
  int tid = threadIdx.x;
  int tq = (tid & 15) * 4;
  for (int ci = 0; ci < 4; ci++) {
    int c = ci * 16 + (tid >> 4);
    float4 v = *(const float4*)&x[((size_t)b * DIMC + c0 + c) * TT + t0 + tq];
    tile[c][tq] = v.x; tile[c][tq + 1] = v.y; tile[c][tq + 2] = v.z; tile[c][tq + 3] = v.w;
  }
  __syncthreads();
  for (int it = 0; it < 2; it++) {
    int t = it * 32 + (tid >> 3);
    int cg = tid & 7;
    int g = b * TT + t0 + t;
    float mu = mean[g], rs = rstd[g];
    BV u;
    for (int k = 0; k < 8; k++) {
      int c = cg * 8 + k;
      float v = (tile[c][t] - mu) * rs * lnw[c0 + c] + lnb[c0 + c];
      u.h[k] = __float2bfloat16(v);
    }
    *(b16x8*)(h + (size_t)g * DIMC + c0 + cg * 8) = u.v;
  }
}

// ---------------- weight fp32 -> bf16 cast ----------------------------------
__global__ void k_cast(const float* __restrict__ wqkv, const float* __restrict__ wout,
                       bf16* __restrict__ wqkvb, bf16* __restrict__ woutb) {
  size_t i = (size_t)blockIdx.x * 256 + threadIdx.x;
  if (i < (size_t)NQKV * DIMC) wqkvb[i] = __float2bfloat16(wqkv[i]);
  if (i < (size_t)DIMC * DIMC) woutb[i] = __float2bfloat16(wout[i]);
}

// ---- shared GEMM K-loop: BK=64, XOR-swizzled LDS, 128x128 tile -------------
// As/Bs rows are 64 bf16 (8 chunks of 8); chunk slot = kchunk ^ (row&7).
#define GEMM_KLOOP(A_, B_, K_)                                                   \
  for (int k0 = 0; k0 < (K_); k0 += 64) {                                        \
    _Pragma("unroll")                                                            \
    for (int r = 0; r < 4; r++) {                                                \
      int chunk = r * 4 + wave;                                                  \
      int row = chunk * 8 + srow;                                                \
      gload_lds16((A_) + (size_t)(m0 + row) * (K_) + k0 + scol,                  \
                  As + chunk * 512 + lane * 8);                                  \
      gload_lds16((B_) + (size_t)(n0 + row) * (K_) + k0 + scol,                  \
                  Bs + chunk * 512 + lane * 8);                                  \
    }                                                                            \
    __syncthreads();                                                             \
    _Pragma("unroll")                                                            \
    for (int s = 0; s < 2; s++) {                                                \
      b16x8 af[4], bfr[4];                                                       \
      _Pragma("unroll")                                                          \
      for (int i = 0; i < 4; i++) {                                              \
        int row = wm + i * 16 + lr;                                              \
        af[i] = *(const b16x8*)(As + row * 64 + ((((s << 2) + quad) ^ (row & 7)) << 3)); \
      }                                                                          \
      _Pragma("unroll")                                                          \
      for (int j = 0; j < 4; j++) {                                              \
        int row = wn + j * 16 + lr;                                              \
        bfr[j] = *(const b16x8*)(Bs + row * 64 + ((((s << 2) + quad) ^ (row & 7)) << 3)); \
      }                                                                          \
      _Pragma("unroll")                                                          \
      for (int i = 0; i < 4; i++)                                                \
        _Pragma("unroll")                                                        \
        for (int j = 0; j < 4; j++)                                              \
          acc[i][j] = __builtin_amdgcn_mfma_f32_16x16x32_bf16(af[i], bfr[j], acc[i][j], 0, 0, 0); \
    }                                                                            \
    __syncthreads();                                                             \
  }

// ---------------- QKV GEMM: C[M,N] = A[M,K] * B[N,K]^T, bf16 out ------------
__global__ __launch_bounds__(256) void k_gemm_bt(const bf16* __restrict__ A,
                                                 const bf16* __restrict__ Bm,
                                                 bf16* __restrict__ C,
                                                 int M, int N, int K) {
  __shared__ __align__(16) char smem[32768];
  bf16* As = (bf16*)smem;            // 128 x 64
  bf16* Bs = (bf16*)(smem + 16384);  // 128 x 64
  bf16* Cs = (bf16*)smem;            // 128 x 128 epilogue repack
  int tid = threadIdx.x;
  int wave = tid >> 6, lane = tid & 63;
  int m0 = blockIdx.y * 128, n0 = blockIdx.x * 128;
  int wm = (wave >> 1) * 64, wn = (wave & 1) * 64;
  int lr = lane & 15, quad = lane >> 4;
  int srow = lane >> 3;                    // 0..7
  int scol = ((lane & 7) ^ srow) * 8;      // swizzled global k-chunk

  f32x4 acc[4][4];
#pragma unroll
  for (int i = 0; i < 4; i++)
#pragma unroll
    for (int j = 0; j < 4; j++) acc[i][j] = (f32x4){0.f, 0.f, 0.f, 0.f};

  GEMM_KLOOP(A, Bm, K)

  // epilogue: repack via LDS, coalesced b16x8 stores
#pragma unroll
  for (int i = 0; i < 4; i++)
#pragma unroll
    for (int j = 0; j < 4; j++)
#pragma unroll
      for (int r = 0; r < 4; r++)
        Cs[(wm + i * 16 + quad * 4 + r) * 128 + wn + j * 16 + lr] =
            __float2bfloat16(acc[i][j][r]);
  __syncthreads();
#pragma unroll
  for (int it = 0; it < 8; it++) {
    int row = it * 16 + (tid >> 4), cg = tid & 15;
    *(b16x8*)(C + (size_t)(m0 + row) * N + n0 + cg * 8) = *(b16x8*)(Cs + row * 128 + cg * 8);
  }
}

// ------ out-proj GEMM fused with transpose + residual, fp32 out -------------
__global__ __launch_bounds__(256) void k_gemm_out(const bf16* __restrict__ A,
                                                  const bf16* __restrict__ Bm,
                                                  const float* __restrict__ x,
                                                  float* __restrict__ out) {
  const int K = DIMC, N = DIMC;
  __shared__ __align__(16) char smem[32768];
  bf16* As = (bf16*)smem;
  bf16* Bs = (bf16*)(smem + 16384);
  float* ls = (float*)smem;          // [32][140] fp32 transpose buffer
  int tid = threadIdx.x;
  int wave = tid >> 6, lane = tid & 63;
  int m0 = blockIdx.y * 128, n0 = blockIdx.x * 128;
  int wm = (wave >> 1) * 64, wn = (wave & 1) * 64;
  int lr = lane & 15, quad = lane >> 4;
  int srow = lane >> 3;
  int scol = ((lane & 7) ^ srow) * 8;

  f32x4 acc[4][4];
#pragma unroll
  for (int i = 0; i < 4; i++)
#pragma unroll
    for (int j = 0; j < 4; j++) acc[i][j] = (f32x4){0.f, 0.f, 0.f, 0.f};

  GEMM_KLOOP(A, Bm, K)

  // epilogue: 4 chunks of 32 channels; transpose through LDS, add residual
  int b = m0 >> 13, t0 = m0 & (TT - 1);
  int tl = tid & 31, cc = tid >> 5;    // tl: token quad-lane, cc: 0..7
  for (int ch = 0; ch < 4; ch++) {
    __syncthreads();
    if ((ch >> 1) == (wave & 1)) {
      int jb = (ch & 1) * 2;
#pragma unroll
      for (int jj = 0; jj < 2; jj++)
#pragma unroll
        for (int i = 0; i < 4; i++)
#pragma unroll
          for (int r = 0; r < 4; r++)
            ls[(jj * 16 + lr) * 140 + wm + i * 16 + quad * 4 + r] = acc[i][jb + jj][r];
    }
    __syncthreads();
#pragma unroll
    for (int cit = 0; cit < 4; cit++) {
      int c = cit * 8 + cc;
      float4 v = *(float4*)(ls + c * 140 + tl * 4);
      size_t o = ((size_t)(b * DIMC + n0 + ch * 32 + c)) * TT + t0 + tl * 4;
      float4 xr = *(const float4*)(x + o);
      v.x += xr.x; v.y += xr.y; v.z += xr.z; v.w += xr.w;
      *(float4*)(out + o) = v;
    }
  }
}

// ---------------- attention: one block per (b, head, window) ----------------
__global__ __launch_bounds__(256) void k_attn(const bf16* __restrict__ qkv,
                                              bf16* __restrict__ att) {
  __shared__ __align__(16) char smem[54272];
  bf16* qs = (bf16*)smem;
  bf16* ks = (bf16*)(smem + 18432);
  bf16* vt = (bf16*)(smem + 36864);
  bf16* ps = (bf16*)smem;

  const int tid = threadIdx.x;
  const int wdw = blockIdx.x, hh = blockIdx.y, b = blockIdx.z;
  const size_t base = ((size_t)(b * TT + wdw * WIN)) * NQKV + hh * DH;

  for (int idx = tid; idx < 128 * 32; idx += 256) {
    int row = idx >> 5, j = idx & 31;
    float invf = exp2f(-0.41524101186f * (float)j);
    float fr = (float)row * invf;
    float sv, cv;
    __sincosf(fr, &sv, &cv);
    const bf16* qp = qkv + base + (size_t)row * NQKV;
    float q0 = __bfloat162float(qp[j]);
    float q1 = __bfloat162float(qp[j + 32]);
    qs[row * 72 + j]      = __float2bfloat16(q0 * cv - q1 * sv);
    qs[row * 72 + j + 32] = __float2bfloat16(q1 * cv + q0 * sv);
    float ka = __bfloat162float(qp[1024 + j]);
    float kb = __bfloat162float(qp[1024 + j + 32]);
    ks[row * 72 + j]      = __float2bfloat16(ka * cv - kb * sv);
    ks[row * 72 + j + 32] = __float2bfloat16(kb * cv + ka * sv);
  }
  for (int idx = tid; idx < 128 * 64; idx += 256) {
    int row = idx >> 6, d = idx & 63;
    vt[d * 136 + row] = qkv[base + (size_t)row * NQKV + 2048 + d];
  }
  __syncthreads();

  const int wid = tid >> 6, lane = tid & 63;
  const int lr = lane & 15, quad = lane >> 4;

  f32x4 sa[2][8];
#pragma unroll
  for (int i = 0; i < 2; i++)
#pragma unroll
    for (int nt = 0; nt < 8; nt++) sa[i][nt] = (f32x4){0.f, 0.f, 0.f, 0.f};

  b16x8 aq[2][2];
#pragma unroll
  for (int i = 0; i < 2; i++)
#pragma unroll
    for (int s = 0; s < 2; s++)
      aq[i][s] = *(const b16x8*)(qs + (wid * 32 + i * 16 + lr) * 72 + s * 32 + quad * 8);
#pragma unroll
  for (int nt = 0; nt < 8; nt++) {
    b16x8 b0 = *(const b16x8*)(ks + (nt * 16 + lr) * 72 + quad * 8);
    b16x8 b1 = *(const b16x8*)(ks + (nt * 16 + lr) * 72 + 32 + quad * 8);
#pragma unroll
    for (int i = 0; i < 2; i++) {
      sa[i][nt] = __builtin_amdgcn_mfma_f32_16x16x32_bf16(aq[i][0], b0, sa[i][nt], 0, 0, 0);
      sa[i][nt] = __builtin_amdgcn_mfma_f32_16x16x32_bf16(aq[i][1], b1, sa[i][nt], 0, 0, 0);
    }
  }
  __syncthreads();

#pragma unroll
  for (int i = 0; i < 2; i++) {
#pragma unroll
    for (int r = 0; r < 4; r++) {
      float vals[8];
      float mx = -1e30f;
#pragma unroll
      for (int nt = 0; nt < 8; nt++) { vals[nt] = sa[i][nt][r] * 0.125f; mx = fmaxf(mx, vals[nt]); }
      for (int m = 1; m < 16; m <<= 1) mx = fmaxf(mx, __shfl_xor(mx, m, 16));
      float sum = 0.f;
#pragma unroll
      for (int nt = 0; nt < 8; nt++) { vals[nt] = __expf(vals[nt] - mx); sum += vals[nt]; }
      for (int m = 1; m < 16; m <<= 1) sum += __shfl_xor(sum, m, 16);
      float inv = 1.0f / sum;
      int row = wid * 32 + i * 16 + quad * 4 + r;
#pragma unroll
      for (int nt = 0; nt < 8; nt++)
        ps[row * 136 + nt * 16 + lr] = __float2bfloat16(vals[nt] * inv);
    }
  }
  __syncthreads();

  f32x4 oa[2][4];
#pragma unroll
  for (int i = 0; i < 2; i++)
#pragma unroll
    for (int nt = 0; nt < 4; nt++) oa[i][nt] = (f32x4){0.f, 0.f, 0.f, 0.f};
#pragma unroll
  for (int s = 0; s < 4; s++) {
    b16x8 ap[2];
#pragma unroll
    for (int i = 0; i < 2; i++)
      ap[i] = *(const b16x8*)(ps + (wid * 32 + i * 16 + lr) * 136 + s * 32 + quad * 8);
#pragma unroll
    for (int nt = 0; nt < 4; nt++) {
      b16x8 bv = *(const b16x8*)(vt + (nt * 16 + lr) * 136 + s * 32 + quad * 8);
#pragma unroll
      for (int i = 0; i < 2; i++)
        oa[i][nt] = __builtin_amdgcn_mfma_f32_16x16x32_bf16(ap[i], bv, oa[i][nt], 0, 0, 0);
    }
  }
#pragma unroll
  for (int i = 0; i < 2; i++)
#pragma unroll
    for (int nt = 0; nt < 4; nt++) {
      int row = wid * 32 + i * 16 + quad * 4;
#pragma unroll
      for (int r = 0; r < 4; r++)
        att[((size_t)(b * TT + wdw * WIN + row + r)) * DIMC + hh * DH + nt * 16 + lr] =
            __float2bfloat16(oa[i][nt][r]);
    }
}

extern "C" void kernel_launch(void* const* d_in, const int* in_sizes, int n_in,
                              void* d_out, int out_size, void* d_ws, size_t ws_size,
                              hipStream_t stream) {
  const float* x    = (const float*)d_in[0];
  const float* lnw  = (const float*)d_in[1];
  const float* lnb  = (const float*)d_in[2];
  const float* wqkv = (const float*)d_in[3];
  const float* wout = (const float*)d_in[4];
  float* out = (float*)d_out;

  char* ws = (char*)d_ws;
  float* psum  = (float*)(ws);                                  // 1 MiB
  float* psq   = (float*)(ws + (size_t)1  * 1024 * 1024);      // 1 MiB
  float* meanp = (float*)(ws + (size_t)2  * 1024 * 1024);      // 128 KiB
  float* rstdp = (float*)(ws + (size_t)2  * 1024 * 1024 + 131072);
  bf16*  wqkvb = (bf16*) (ws + (size_t)4  * 1024 * 1024);      // 6 MiB
  bf16*  woutb = (bf16*) (ws + (size_t)10 * 1024 * 1024);      // 2 MiB
  bf16*  h     = (bf16*) (ws + (size_t)12 * 1024 * 1024);      // 64 MiB
  bf16*  qkv   = (bf16*) (ws + (size_t)76 * 1024 * 1024);      // 192 MiB
  bf16*  att   = h;    // h consumed by QKV GEMM before attention writes

  k_stats_partial<<<dim3(NTOK / 1024, 8), 256, 0, stream>>>(x, psum, psq);
  k_stats_final<<<dim3(NTOK / 1024), 256, 0, stream>>>(psum, psq, meanp, rstdp);
  k_norm_t<<<dim3(TT / 64, DIMC / 64, BB), 256, 0, stream>>>(x, meanp, rstdp, lnw, lnb, h);
  k_cast<<<dim3((NQKV * DIMC) / 256), 256, 0, stream>>>(wqkv, wout, wqkvb, woutb);
  k_gemm_bt<<<dim3(NQKV / 128, NTOK / 128), 256, 0, stream>>>(h, wqkvb, qkv, NTOK, NQKV, DIMC);
  k_attn<<<dim3(TT / WIN, NH, BB), 256, 0, stream>>>(qkv, att);
  k_gemm_out<<<dim3(DIMC / 128, NTOK / 128), 256, 0, stream>>>(att, woutb, x, out);
}